// Round 4
// baseline (142.659 us; speedup 1.0000x reference)
//
#include <hip/hip_runtime.h>

// WaveletLayer: db2 DWT -> gain -> IDWT -> ReLU fused as one 6-tap stencil.
// 8 outputs per thread: 2 aligned float4 x-loads + 2 float2 halo loads
// (1.5x read amplification), 5 scalar gain loads (ker rows are 4B-aligned:
// L=2049 odd), 2 nontemporal 16B stores (output is write-once).
// B=4096 rows, N=4096, L=2049.

#define NN 4096
#define LL 2049
#define TPR 512  // threads per row, 8 outputs each

typedef float v4f __attribute__((ext_vector_type(4)));

__global__ __launch_bounds__(256) void wavelet_fused(const float* __restrict__ x,
                                                     const float* __restrict__ ker,
                                                     float* __restrict__ out) {
    const int row = blockIdx.y;
    const int t   = blockIdx.x * 256 + threadIdx.x;   // 0..511
    const int base = 8 * t;

    // db2 decomposition taps
    const float lo0 = -0.12940952255126037f, lo1 = 0.22414386804185735f,
                lo2 =  0.8365163037378079f,  lo3 = 0.48296291314453416f;
    const float hi0 = -0.48296291314453416f, hi1 = 0.8365163037378079f,
                hi2 = -0.22414386804185735f, hi3 = -0.12940952255126037f;

    const float* xrow = x + (size_t)row * NN;
    const bool first = (t == 0);
    const bool last  = (t == TPR - 1);

    // owned x elements X(base..base+7)
    const float4 c0 = *(const float4*)(xrow + base);
    const float4 c1 = *(const float4*)(xrow + base + 4);
    // halos (clamped addresses stay 8B-aligned; edge threads swap components
    // because symmetric padding reverses order)
    const int la = first ? 0 : (base - 2);
    const int ra = last ? (NN - 2) : (base + 8);
    const float2 hl = *(const float2*)(xrow + la);
    const float2 hr = *(const float2*)(xrow + ra);

    float E[12];
    E[0] = first ? hl.y : hl.x;   // X(base-2)  [X(-2)=x[1]]
    E[1] = first ? hl.x : hl.y;   // X(base-1)  [X(-1)=x[0]]
    E[2] = c0.x; E[3] = c0.y; E[4] = c0.z; E[5] = c0.w;
    E[6] = c1.x; E[7] = c1.y; E[8] = c1.z; E[9] = c1.w;
    E[10] = last ? hr.y : hr.x;   // X(base+8)  [X(4096)=x[4095]]
    E[11] = last ? hr.x : hr.y;   // X(base+9)  [X(4097)=x[4094]]

    // gains g[4t .. 4t+4] (4t+4 <= 2048 always valid)
    const float* krow = ker + (size_t)row * LL + 4 * t;
    float g[5];
    #pragma unroll
    for (int i = 0; i < 5; ++i) g[i] = krow[i];

    // analysis + gain: A[i] = g[i]*cA[4t+i], D[i] = g[i]*cD[4t+i]
    float A[5], D[5];
    #pragma unroll
    for (int i = 0; i < 5; ++i) {
        const float e0 = E[2 * i], e1 = E[2 * i + 1], e2 = E[2 * i + 2], e3 = E[2 * i + 3];
        const float cA = lo3 * e0 + lo2 * e1 + lo1 * e2 + lo0 * e3;
        const float cD = hi3 * e0 + hi2 * e1 + hi1 * e2 + hi0 * e3;
        A[i] = g[i] * cA;
        D[i] = g[i] * cD;
    }

    // synthesis + ReLU
    float y[8];
    #pragma unroll
    for (int i = 0; i < 4; ++i) {
        float ye = lo1 * A[i] + lo3 * A[i + 1] + hi1 * D[i] + hi3 * D[i + 1];
        float yo = lo0 * A[i] + lo2 * A[i + 1] + hi0 * D[i] + hi2 * D[i + 1];
        y[2 * i]     = fmaxf(ye, 0.0f);
        y[2 * i + 1] = fmaxf(yo, 0.0f);
    }

    float* orow = out + (size_t)row * NN + base;
    v4f w0 = { y[0], y[1], y[2], y[3] };
    v4f w1 = { y[4], y[5], y[6], y[7] };
    __builtin_nontemporal_store(w0, (v4f*)orow);
    __builtin_nontemporal_store(w1, (v4f*)(orow + 4));
}

extern "C" void kernel_launch(void* const* d_in, const int* in_sizes, int n_in,
                              void* d_out, int out_size, void* d_ws, size_t ws_size,
                              hipStream_t stream) {
    const float* x   = (const float*)d_in[0];
    const float* ker = (const float*)d_in[1];
    float* out = (float*)d_out;
    wavelet_fused<<<dim3(TPR / 256, 4096), dim3(256), 0, stream>>>(x, ker, out);
}

// Round 5
// 139.902 us; speedup vs baseline: 1.0197x; 1.0197x over previous
//
#include <hip/hip_runtime.h>

// WaveletLayer: db2 DWT -> gain -> IDWT -> ReLU fused as one 6-tap stencil.
// Each thread produces 8 outputs in each of TWO rows (2 independent load
// batches in flight per wave -> better latency hiding, half the waves).
// Per row: 2 aligned float4 x-loads + 2 float2 halo loads + 5 scalar gains.
// Plain float4 stores (nontemporal hurt: partial-line HBM writes).
// B=4096 rows, N=4096, L=2049.

#define NN 4096
#define LL 2049
#define TPR 512  // threads per row, 8 outputs each

__global__ __launch_bounds__(256) void wavelet_fused(const float* __restrict__ x,
                                                     const float* __restrict__ ker,
                                                     float* __restrict__ out) {
    const int row0 = 2 * blockIdx.y;          // rows row0, row0+1
    const int t    = blockIdx.x * 256 + threadIdx.x;   // 0..511
    const int base = 8 * t;

    // db2 decomposition taps
    const float lo0 = -0.12940952255126037f, lo1 = 0.22414386804185735f,
                lo2 =  0.8365163037378079f,  lo3 = 0.48296291314453416f;
    const float hi0 = -0.48296291314453416f, hi1 = 0.8365163037378079f,
                hi2 = -0.22414386804185735f, hi3 = -0.12940952255126037f;

    const bool first = (t == 0);
    const bool last  = (t == TPR - 1);
    const int la = first ? 0 : (base - 2);
    const int ra = last ? (NN - 2) : (base + 8);

    // ---- issue ALL loads for both rows before any compute ----
    const float* xr0 = x + (size_t)row0 * NN;
    const float* xr1 = xr0 + NN;
    const float4 c0a = *(const float4*)(xr0 + base);
    const float4 c1a = *(const float4*)(xr0 + base + 4);
    const float2 hla = *(const float2*)(xr0 + la);
    const float2 hra = *(const float2*)(xr0 + ra);
    const float4 c0b = *(const float4*)(xr1 + base);
    const float4 c1b = *(const float4*)(xr1 + base + 4);
    const float2 hlb = *(const float2*)(xr1 + la);
    const float2 hrb = *(const float2*)(xr1 + ra);

    const float* kr0 = ker + (size_t)row0 * LL + 4 * t;
    const float* kr1 = kr0 + LL;
    float ga[5], gb[5];
    #pragma unroll
    for (int i = 0; i < 5; ++i) ga[i] = kr0[i];
    #pragma unroll
    for (int i = 0; i < 5; ++i) gb[i] = kr1[i];

    float* orow0 = out + (size_t)row0 * NN + base;
    float* orow1 = orow0 + NN;

    #pragma unroll
    for (int r = 0; r < 2; ++r) {
        const float4 c0 = r ? c0b : c0a;
        const float4 c1 = r ? c1b : c1a;
        const float2 hl = r ? hlb : hla;
        const float2 hr = r ? hrb : hra;
        const float* g  = r ? gb : ga;

        float E[12];
        E[0] = first ? hl.y : hl.x;   // X(base-2)  [X(-2)=x[1]]
        E[1] = first ? hl.x : hl.y;   // X(base-1)  [X(-1)=x[0]]
        E[2] = c0.x; E[3] = c0.y; E[4] = c0.z; E[5] = c0.w;
        E[6] = c1.x; E[7] = c1.y; E[8] = c1.z; E[9] = c1.w;
        E[10] = last ? hr.y : hr.x;   // X(base+8)  [X(4096)=x[4095]]
        E[11] = last ? hr.x : hr.y;   // X(base+9)  [X(4097)=x[4094]]

        float A[5], D[5];
        #pragma unroll
        for (int i = 0; i < 5; ++i) {
            const float e0 = E[2 * i], e1 = E[2 * i + 1];
            const float e2 = E[2 * i + 2], e3 = E[2 * i + 3];
            const float cA = lo3 * e0 + lo2 * e1 + lo1 * e2 + lo0 * e3;
            const float cD = hi3 * e0 + hi2 * e1 + hi1 * e2 + hi0 * e3;
            A[i] = g[i] * cA;
            D[i] = g[i] * cD;
        }

        float y[8];
        #pragma unroll
        for (int i = 0; i < 4; ++i) {
            float ye = lo1 * A[i] + lo3 * A[i + 1] + hi1 * D[i] + hi3 * D[i + 1];
            float yo = lo0 * A[i] + lo2 * A[i + 1] + hi0 * D[i] + hi2 * D[i + 1];
            y[2 * i]     = fmaxf(ye, 0.0f);
            y[2 * i + 1] = fmaxf(yo, 0.0f);
        }

        float* orow = r ? orow1 : orow0;
        *(float4*)(orow)     = make_float4(y[0], y[1], y[2], y[3]);
        *(float4*)(orow + 4) = make_float4(y[4], y[5], y[6], y[7]);
    }
}

extern "C" void kernel_launch(void* const* d_in, const int* in_sizes, int n_in,
                              void* d_out, int out_size, void* d_ws, size_t ws_size,
                              hipStream_t stream) {
    const float* x   = (const float*)d_in[0];
    const float* ker = (const float*)d_in[1];
    float* out = (float*)d_out;
    wavelet_fused<<<dim3(TPR / 256, 2048), dim3(256), 0, stream>>>(x, ker, out);
}

// Round 6
// 139.135 us; speedup vs baseline: 1.0253x; 1.0055x over previous
//
#include <hip/hip_runtime.h>

// WaveletLayer: db2 DWT -> gain -> IDWT -> ReLU fused as one 6-tap stencil.
// One 1024-thread block per row. Global traffic is copy-pure: per thread
// exactly 1 dense float4 x-load, 2 dense dword gain loads, 1 dense float4
// store. Row staged in LDS (16KB x + 8.2KB gains, one barrier); stencil
// reads come from LDS as dense-stride b128 (conflict-free). Symmetric-pad
// boundary handled entirely in-LDS (full-row block => no halo).
// B=4096 rows, N=4096, L=2049.

#define NN 4096
#define LL 2049

__global__ __launch_bounds__(1024) void wavelet_fused(const float* __restrict__ x,
                                                      const float* __restrict__ ker,
                                                      float* __restrict__ out) {
    __shared__ float s_x[NN];
    __shared__ float s_g[LL];

    const int row = blockIdx.x;
    const int i   = threadIdx.x;   // 0..1023, produces outputs 4i..4i+3

    // db2 decomposition taps
    const float lo0 = -0.12940952255126037f, lo1 = 0.22414386804185735f,
                lo2 =  0.8365163037378079f,  lo3 = 0.48296291314453416f;
    const float hi0 = -0.48296291314453416f, hi1 = 0.8365163037378079f,
                hi2 = -0.22414386804185735f, hi3 = -0.12940952255126037f;

    // ---- stage row into LDS: fully dense, coalesced ----
    const float4* x4 = (const float4*)(x + (size_t)row * NN);
    ((float4*)s_x)[i] = x4[i];
    const float* krow = ker + (size_t)row * LL;
    s_g[i]        = krow[i];
    s_g[i + 1024] = krow[i + 1024];
    if (i == 0) s_g[2048] = krow[2048];
    __syncthreads();

    // ---- stencil window X(4i-2 .. 4i+5), X = symmetric-padded row ----
    // All three LDS reads are 16B-aligned b128 with 16B lane stride
    // (conflict-free); edge threads clamp the address and swap components
    // (symmetric padding reverses order).
    const bool first = (i == 0);
    const bool last  = (i == 1023);
    const float4 L = *(const float4*)(s_x + (first ? 0 : 4 * i - 4));
    const float4 C = *(const float4*)(s_x + 4 * i);
    const float4 R = *(const float4*)(s_x + (last ? 4092 : 4 * i + 4));

    const float e0 = first ? L.y : L.z;   // X(4i-2)  [X(-2)=x[1]]
    const float e1 = first ? L.x : L.w;   // X(4i-1)  [X(-1)=x[0]]
    const float e2 = C.x, e3 = C.y, e4 = C.z, e5 = C.w;
    const float e6 = last ? R.w : R.x;    // X(4i+4)  [X(4096)=x[4095]]
    const float e7 = last ? R.z : R.y;    // X(4i+5)  [X(4097)=x[4094]]

    // gains g[2i], g[2i+1], g[2i+2]: dense b64 + 2-way-aliased dword (free)
    const float2 gp = *(const float2*)(s_g + 2 * i);
    const float  g2 = s_g[2 * i + 2];

    // analysis + gain: cA[j] = lo3*X(2j-2)+lo2*X(2j-1)+lo1*X(2j)+lo0*X(2j+1)
    const float cA0 = lo3 * e0 + lo2 * e1 + lo1 * e2 + lo0 * e3;
    const float cD0 = hi3 * e0 + hi2 * e1 + hi1 * e2 + hi0 * e3;
    const float cA1 = lo3 * e2 + lo2 * e3 + lo1 * e4 + lo0 * e5;
    const float cD1 = hi3 * e2 + hi2 * e3 + hi1 * e4 + hi0 * e5;
    const float cA2 = lo3 * e4 + lo2 * e5 + lo1 * e6 + lo0 * e7;
    const float cD2 = hi3 * e4 + hi2 * e5 + hi1 * e6 + hi0 * e7;

    const float A0 = gp.x * cA0, D0 = gp.x * cD0;
    const float A1 = gp.y * cA1, D1 = gp.y * cD1;
    const float A2 = g2   * cA2, D2 = g2   * cD2;

    // synthesis + ReLU
    float y0 = lo1 * A0 + lo3 * A1 + hi1 * D0 + hi3 * D1;
    float y1 = lo0 * A0 + lo2 * A1 + hi0 * D0 + hi2 * D1;
    float y2 = lo1 * A1 + lo3 * A2 + hi1 * D1 + hi3 * D2;
    float y3 = lo0 * A1 + lo2 * A2 + hi0 * D1 + hi2 * D2;
    y0 = fmaxf(y0, 0.0f);
    y1 = fmaxf(y1, 0.0f);
    y2 = fmaxf(y2, 0.0f);
    y3 = fmaxf(y3, 0.0f);

    float4* out4 = (float4*)(out + (size_t)row * NN);
    out4[i] = make_float4(y0, y1, y2, y3);
}

extern "C" void kernel_launch(void* const* d_in, const int* in_sizes, int n_in,
                              void* d_out, int out_size, void* d_ws, size_t ws_size,
                              hipStream_t stream) {
    const float* x   = (const float*)d_in[0];
    const float* ker = (const float*)d_in[1];
    float* out = (float*)d_out;
    wavelet_fused<<<dim3(4096), dim3(1024), 0, stream>>>(x, ker, out);
}